// Round 5
// baseline (362.483 us; speedup 1.0000x reference)
//
#include <hip/hip_runtime.h>
#include <hip/hip_bf16.h>
#include <stdint.h>

// B=4, N=8192, E=1024, D=64 ; ROWS = 32768
// out = ((x@wq^T) @ (K^T V) * sqrt(3/64)) @ wo^T
// Precision: weights exact in bf16; activations split hi/lo bf16 -> fp32 MFMA acc.
//
// R5: barrier-free rebuild. Every GEMM wave is fully independent:
//  - K1: A-frags straight from global x (full-line coalescing by construction),
//    2-deep A prefetch, 1-deep B prefetch, B shared through L1 by the block's
//    4 waves. No LDS, no barriers.
//  - K3: ctx(Q@E) + out(ctx@wo^T) fused per wave; transpose via wave-private
//    LDS (lgkmcnt wait only, no s_barrier).

typedef __bf16 bf16x8 __attribute__((ext_vector_type(8)));
typedef float  f32x4  __attribute__((ext_vector_type(4)));

#define MFMA_BF16(A, Bb, C) __builtin_amdgcn_mfma_f32_16x16x32_bf16(A, Bb, C, 0, 0, 0)

// ---------------------------------------------------------------------------
// P0: flat fp32->bf16 cast of [wq|wk|wv|wo] -> Wb[192][1024] ++ Wob[1024][64].
// ---------------------------------------------------------------------------
__global__ __launch_bounds__(128) void prep_kernel(
    const float* __restrict__ wq, const float* __restrict__ wk,
    const float* __restrict__ wv, const float* __restrict__ wo,
    __bf16* __restrict__ Wb)
{
    const int gid = blockIdx.x * 128 + threadIdx.x;      // 0..32767
    const int e0  = gid * 8;
    const float* src = (e0 < 65536)  ? wq + e0
                     : (e0 < 131072) ? wk + (e0 - 65536)
                     : (e0 < 196608) ? wv + (e0 - 131072)
                                     : wo + (e0 - 196608);
    float w[8];
    *(float4*)&w[0] = *(const float4*)(src);
    *(float4*)&w[4] = *(const float4*)(src + 4);
    bf16x8 wb;
#pragma unroll
    for (int j = 0; j < 8; ++j) wb[j] = (__bf16)w[j];
    *(bf16x8*)&Wb[e0] = wb;
}

// ---------------------------------------------------------------------------
// K1: QKV GEMM, barrier-free.  1024 blocks x 256 thr.
// block = 64-row slab x 96-col group; wave = 16 rows x 96 cols (6 frags).
// 32 K-steps of K=32.  A: global fp32 -> hi/lo in reg (2-deep prefetch).
// B: bf16 frags from L2/L1 (1-deep prefetch).  12 MFMA / step.
// ---------------------------------------------------------------------------
__global__ __launch_bounds__(256) void qkv_kernel(
    const float* __restrict__ x, const __bf16* __restrict__ Wb,
    float* __restrict__ Qf, float* __restrict__ Kf, float* __restrict__ Vf)
{
    const int tid  = threadIdx.x;
    const int lane = tid & 63;
    const int wid  = tid >> 6;
    const int lr   = lane & 15;
    const int kg   = lane >> 4;
    const int slab = blockIdx.x >> 1;
    const int c0   = (blockIdx.x & 1) * 96;
    const int row0 = slab * 64 + wid * 16;

    const float* xrow = &x[(size_t)(row0 + lr) * 1024 + kg * 8];

    f32x4 acc[6];
#pragma unroll
    for (int i = 0; i < 6; ++i) acc[i] = (f32x4){0.f, 0.f, 0.f, 0.f};

    float4 pa0, pa1, qa0, qa1;          // A prefetch, depth 2 (even/odd)
    bf16x8 Bc[6], Bn[6];                // B prefetch, depth 1

#define LOAD_A(B0, B1, STP) {                                                  \
        const float* ap_ = xrow + (STP) * 32;                                  \
        B0 = *(const float4*)(ap_);                                            \
        B1 = *(const float4*)(ap_ + 4); }
#define LOAD_B(BARR, STP) {                                                    \
        _Pragma("unroll")                                                      \
        for (int bn_ = 0; bn_ < 6; ++bn_)                                      \
            BARR[bn_] = *(const bf16x8*)&Wb[(size_t)(c0 + bn_ * 16 + lr) * 1024 \
                                            + (STP) * 32 + kg * 8]; }
#define K1_STEP(S, A0_, A1_, BC, BN) {                                         \
        if ((S) + 1 < 32) LOAD_B(BN, (S) + 1);                                 \
        bf16x8 Ah_, Al_;                                                       \
        const float* fp_ = (const float*)&A0_;                                 \
        _Pragma("unroll")                                                      \
        for (int j_ = 0; j_ < 4; ++j_) {                                       \
            const unsigned int bb_ = __float_as_uint(fp_[j_]);                 \
            Ah_[j_] = __builtin_bit_cast(__bf16, (unsigned short)(bb_ >> 16)); \
            Al_[j_] = (__bf16)(fp_[j_] - __uint_as_float(bb_ & 0xffff0000u));  \
        }                                                                      \
        const float* gp_ = (const float*)&A1_;                                 \
        _Pragma("unroll")                                                      \
        for (int j_ = 0; j_ < 4; ++j_) {                                       \
            const unsigned int bb_ = __float_as_uint(gp_[j_]);                 \
            Ah_[4 + j_] = __builtin_bit_cast(__bf16, (unsigned short)(bb_ >> 16)); \
            Al_[4 + j_] = (__bf16)(gp_[j_] - __uint_as_float(bb_ & 0xffff0000u)); \
        }                                                                      \
        if ((S) + 2 < 32) LOAD_A(A0_, A1_, (S) + 2);                           \
        _Pragma("unroll")                                                      \
        for (int bn_ = 0; bn_ < 6; ++bn_) {                                    \
            acc[bn_] = MFMA_BF16(Ah_, BC[bn_], acc[bn_]);                      \
            acc[bn_] = MFMA_BF16(Al_, BC[bn_], acc[bn_]);                      \
        } }

    LOAD_A(pa0, pa1, 0);
    LOAD_A(qa0, qa1, 1);
    LOAD_B(Bc, 0);

    for (int s = 0; s < 32; s += 2) {
        K1_STEP(s,     pa0, pa1, Bc, Bn);
        K1_STEP(s + 1, qa0, qa1, Bn, Bc);
    }
#undef LOAD_A
#undef LOAD_B
#undef K1_STEP

    // epilogue: C/D layout col=lane&15, row=(lane>>4)*4+reg
#pragma unroll
    for (int bn = 0; bn < 6; ++bn) {
        const int col  = c0 + bn * 16 + lr;
        const int rowb = row0 + kg * 4;
        float* dst = (col < 64) ? Qf : (col < 128) ? Kf : Vf;
        const int cc = col & 63;
#pragma unroll
        for (int r = 0; r < 4; ++r)
            dst[(size_t)(rowb + r) * 64 + cc] = acc[bn][r];
    }
}

// ---------------------------------------------------------------------------
// K2: partial energy.  part[blk][d][e] = sum over 64 rows of K[n,d]*V[n,e].
// 512 blocks x 256 thr; one barrier; d=lane (stride-1), V reads broadcast.
// ---------------------------------------------------------------------------
__global__ __launch_bounds__(256) void energy_partial_kernel(
    const float* __restrict__ Kf, const float* __restrict__ Vf,
    float* __restrict__ part)
{
    __shared__ float lK[64 * 64];
    __shared__ float lV[64 * 64];
    const int tid  = threadIdx.x;
    const int row0 = blockIdx.x * 64;

#pragma unroll
    for (int i = 0; i < 4; ++i) {
        const int idx = tid + i * 256;           // float4 slot 0..1023
        const int r   = idx >> 4;
        const int c4  = (idx & 15) << 2;
        *(float4*)&lK[r * 64 + c4] = *(const float4*)&Kf[(size_t)(row0 + r) * 64 + c4];
        *(float4*)&lV[r * 64 + c4] = *(const float4*)&Vf[(size_t)(row0 + r) * 64 + c4];
    }
    __syncthreads();

    const int d  = tid & 63;
    const int eb = (tid >> 6) * 16;
    float acc[16];
#pragma unroll
    for (int j = 0; j < 16; ++j) acc[j] = 0.f;

    for (int n = 0; n < 64; ++n) {
        const float kd = lK[n * 64 + d];
        const float4 v0 = *(const float4*)&lV[n * 64 + eb];
        const float4 v1 = *(const float4*)&lV[n * 64 + eb + 4];
        const float4 v2 = *(const float4*)&lV[n * 64 + eb + 8];
        const float4 v3 = *(const float4*)&lV[n * 64 + eb + 12];
        acc[0]  += kd * v0.x; acc[1]  += kd * v0.y; acc[2]  += kd * v0.z; acc[3]  += kd * v0.w;
        acc[4]  += kd * v1.x; acc[5]  += kd * v1.y; acc[6]  += kd * v1.z; acc[7]  += kd * v1.w;
        acc[8]  += kd * v2.x; acc[9]  += kd * v2.y; acc[10] += kd * v2.z; acc[11] += kd * v2.w;
        acc[12] += kd * v3.x; acc[13] += kd * v3.y; acc[14] += kd * v3.z; acc[15] += kd * v3.w;
    }
    float* p = part + (size_t)blockIdx.x * 4096 + d * 64 + eb;
#pragma unroll
    for (int i = 0; i < 4; ++i)
        *(float4*)&p[i * 4] = make_float4(acc[i*4], acc[i*4+1], acc[i*4+2], acc[i*4+3]);
}

// K2b: reduce 128 partials per batch, fold sqrt(3/64), emit E^T hi/lo bf16
// layout Et[b][e*64+d].
__global__ __launch_bounds__(256) void energy_reduce_kernel(
    const float* __restrict__ part, __bf16* __restrict__ Eth, __bf16* __restrict__ Etl)
{
    const int b    = blockIdx.x >> 4;
    const int elem = ((blockIdx.x & 15) << 8) + threadIdx.x;   // d*64+e
    float s = 0.f;
#pragma unroll 8
    for (int c = 0; c < 128; ++c)
        s += part[(size_t)(b * 128 + c) * 4096 + elem];
    s *= 0.2165063509461097f;                                  // sqrt(3/64)
    const int d = elem >> 6, e = elem & 63;
    const __bf16 h = (__bf16)s;
    const __bf16 l = (__bf16)(s - (float)h);
    const size_t o = (size_t)b * 4096 + e * 64 + d;
    Eth[o] = h; Etl[o] = l;
}

// ---------------------------------------------------------------------------
// K3: fused  out = (Q @ E) @ wo^T.   1024 blocks x 256 thr, waves independent.
// wave = 16 rows x 512 cols.  ctx via 24 MFMA; transpose through wave-private
// LDS (lgkmcnt only); out-GEMM: 8 groups of 64 cols, B from L1/L2-hot Wob.
// ---------------------------------------------------------------------------
__global__ __launch_bounds__(256) void out_kernel(
    const float* __restrict__ Qf,
    const __bf16* __restrict__ Eth, const __bf16* __restrict__ Etl,
    const __bf16* __restrict__ Wob, float* __restrict__ out)
{
    __shared__ float ct[4][16 * 68];             // wave-private, padded

    const int tid  = threadIdx.x;
    const int lane = tid & 63;
    const int wid  = tid >> 6;
    const int lr   = lane & 15;
    const int kg   = lane >> 4;
    const int slab = blockIdx.x >> 1;            // 64-row slab
    const int c0   = (blockIdx.x & 1) * 512;
    const int row0 = slab * 64 + wid * 16;
    const int b    = blockIdx.x >> 8;            // batch (256 blocks each)

    // ---- load Q fragment rows, split hi/lo in reg ----
    bf16x8 Qh[2], Ql[2];
#pragma unroll
    for (int ks = 0; ks < 2; ++ks) {
        float qv[8];
        const float* src = &Qf[(size_t)(row0 + lr) * 64 + ks * 32 + kg * 8];
        *(float4*)&qv[0] = *(const float4*)(src);
        *(float4*)&qv[4] = *(const float4*)(src + 4);
#pragma unroll
        for (int j = 0; j < 8; ++j) {
            const unsigned int bb = __float_as_uint(qv[j]);
            Qh[ks][j] = __builtin_bit_cast(__bf16, (unsigned short)(bb >> 16));
            Ql[ks][j] = (__bf16)(qv[j] - __uint_as_float(bb & 0xffff0000u));
        }
    }

    // ---- ctx = Q @ E : 24 MFMA ----
    f32x4 cacc[4];
#pragma unroll
    for (int i = 0; i < 4; ++i) cacc[i] = (f32x4){0.f, 0.f, 0.f, 0.f};
#pragma unroll
    for (int ks = 0; ks < 2; ++ks) {
#pragma unroll
        for (int eb = 0; eb < 4; ++eb) {
            const int e = eb * 16 + lr;
            const bf16x8 Bh = *(const bf16x8*)&Eth[(size_t)b * 4096 + e * 64 + ks * 32 + kg * 8];
            const bf16x8 Bl = *(const bf16x8*)&Etl[(size_t)b * 4096 + e * 64 + ks * 32 + kg * 8];
            cacc[eb] = MFMA_BF16(Qh[ks], Bh, cacc[eb]);
            cacc[eb] = MFMA_BF16(Qh[ks], Bl, cacc[eb]);
            cacc[eb] = MFMA_BF16(Ql[ks], Bh, cacc[eb]);
        }
    }

    // ---- transpose through wave-private LDS (no s_barrier) ----
#pragma unroll
    for (int eb = 0; eb < 4; ++eb)
#pragma unroll
        for (int r = 0; r < 4; ++r)
            ct[wid][(kg * 4 + r) * 68 + eb * 16 + lr] = cacc[eb][r];
    asm volatile("s_waitcnt lgkmcnt(0)" ::: "memory");

    // ---- reload ctx as A-frags, split hi/lo ----
    bf16x8 Ah[2], Al[2];
#pragma unroll
    for (int ks = 0; ks < 2; ++ks) {
        float f[8];
#pragma unroll
        for (int i = 0; i < 2; ++i)
            *(float4*)&f[i * 4] = *(const float4*)&ct[wid][lr * 68 + ks * 32 + kg * 8 + i * 4];
#pragma unroll
        for (int j = 0; j < 8; ++j) {
            const unsigned int bb = __float_as_uint(f[j]);
            Ah[ks][j] = __builtin_bit_cast(__bf16, (unsigned short)(bb >> 16));
            Al[ks][j] = (__bf16)(f[j] - __uint_as_float(bb & 0xffff0000u));
        }
    }

    // ---- out GEMM: 8 groups of 64 cols ----
    for (int g = 0; g < 8; ++g) {
        f32x4 oacc[4];
#pragma unroll
        for (int i = 0; i < 4; ++i) oacc[i] = (f32x4){0.f, 0.f, 0.f, 0.f};
#pragma unroll
        for (int ks = 0; ks < 2; ++ks) {
#pragma unroll
            for (int bn = 0; bn < 4; ++bn) {
                const int col = c0 + g * 64 + bn * 16 + lr;
                const bf16x8 Bw = *(const bf16x8*)&Wob[(size_t)col * 64 + ks * 32 + kg * 8];
                oacc[bn] = MFMA_BF16(Ah[ks], Bw, oacc[bn]);
                oacc[bn] = MFMA_BF16(Al[ks], Bw, oacc[bn]);
            }
        }
#pragma unroll
        for (int bn = 0; bn < 4; ++bn)
#pragma unroll
            for (int r = 0; r < 4; ++r)
                __builtin_nontemporal_store(oacc[bn][r],
                    &out[(size_t)(row0 + kg * 4 + r) * 1024 + c0 + g * 64 + bn * 16 + lr]);
    }
}

extern "C" void kernel_launch(void* const* d_in, const int* in_sizes, int n_in,
                              void* d_out, int out_size, void* d_ws, size_t ws_size,
                              hipStream_t stream)
{
    const float* x  = (const float*)d_in[0];
    const float* wq = (const float*)d_in[1];
    const float* wk = (const float*)d_in[2];
    const float* wv = (const float*)d_in[3];
    const float* wo = (const float*)d_in[4];
    float* out = (float*)d_out;

    char* ws = (char*)d_ws;
    float*  Qf   = (float*)(ws);                          //  8 MB
    float*  Kf   = (float*)(ws + 8388608);                //  8 MB
    float*  Vf   = (float*)(ws + 16777216);               //  8 MB
    float*  part = (float*)(ws + 25165824);               //  8 MB (512*4096*4)
    __bf16* Wb   = (__bf16*)(ws + 33554432);              //  512 KB [192][1024] ++ [1024][64]
    __bf16* Wob  = Wb + 196608;
    __bf16* Eth  = (__bf16*)(ws + 34603008);              //  32 KB
    __bf16* Etl  = (__bf16*)(ws + 34635776);              //  32 KB

    prep_kernel<<<256, 128, 0, stream>>>(wq, wk, wv, wo, Wb);
    qkv_kernel<<<1024, 256, 0, stream>>>(x, Wb, Qf, Kf, Vf);
    energy_partial_kernel<<<512, 256, 0, stream>>>(Kf, Vf, part);
    energy_reduce_kernel<<<64, 256, 0, stream>>>(part, Eth, Etl);
    out_kernel<<<1024, 256, 0, stream>>>(Qf, Eth, Etl, Wob, out);
}